// Round 14
// baseline (3082.937 us; speedup 1.0000x reference)
//
#include <hip/hip_runtime.h>

// ESN recurrence on MI355X: h_t = tanh(x_t @ W_in^T + h_{t-1} @ W_res^T)
// B=64, T=512, I=128, H=2048. Persistent cooperative kernel, 256 WGs (1/CU).
// Logical WG (bg,j): batches [bg*16,+16), rows [j*32,+32).
// R14 = R13 (in-band fp16-LSB tags = truth, flag hints, XCD-local L2 h
// caching w/ leader inv, escalation safety valve) + PER-FRAGMENT STREAMING
// CONSUME: instead of waiting for all 16 producers then doing a monolithic
// load+validate+32-MFMA block, each wave polls its 16 producer flags in one
// vector load, and the moment a subset is ready it loads, validates, and
// MFMAs just those fragments. Early producers' work overlaps waiting for
// stragglers; the post-last-producer tail shrinks from ~1.5us to ~0.3us.
// R13 evidence: FETCH 632->191MB at constant time => latency/straggler-bound,
// not bandwidth-bound; this attacks the straggler tail directly.

#define B_ 64
#define T_ 512
#define I_ 128
#define H_ 2048
#define NWG 256
#define ROWS 32          // output rows per WG
#define BATS 16          // batches per WG
#define WPAD 2056        // 2048 + 8 halves row pad
#define IPAD 136         // 128 + 8 halves row pad
#define PPAD 33          // partial row pad (break 32-bank stride)
#define FSTRIDE 16       // flag stride in dwords (64 B line per producer)

typedef _Float16 f16;
typedef f16 f16x8 __attribute__((ext_vector_type(8)));
typedef float f32x4 __attribute__((ext_vector_type(4)));
typedef unsigned long long u64;
typedef unsigned int u32;
typedef unsigned short u16;
typedef u32 u32x4 __attribute__((ext_vector_type(4)));

#define TAG32 0x00010001u            // mantissa-LSB mask, 2 halves per dword

// LDS layout (bytes):
//   Wres  : ROWS*WPAD*2           = 131584
//   Win_hi: ROWS*IPAD*2           =   8704
//   Win_lo: ROWS*IPAD*2           =   8704
//   part  : 4*BATS*PPAD*4         =   8448
#define LDS_WRES   0
#define LDS_WINHI  131584
#define LDS_WINLO  (131584 + 8704)
#define LDS_PART   (131584 + 17408)
#define LDS_TOTAL  (131584 + 17408 + 8448)

extern "C" __global__ __launch_bounds__(256, 1)
void esn_kernel(const float* __restrict__ x, const float* __restrict__ Win,
                const float* __restrict__ Wres, float* __restrict__ out,
                u16* ht0, u16* ht1, int* flags)
{
    extern __shared__ char lds[];
    f16*   Wr   = (f16*)(lds + LDS_WRES);    // [ROWS][WPAD]
    f16*   Whi  = (f16*)(lds + LDS_WINHI);   // [ROWS][IPAD]
    f16*   Wlo  = (f16*)(lds + LDS_WINLO);   // [ROWS][IPAD]
    float* part = (float*)(lds + LDS_PART);  // [4][BATS][PPAD]

    const int tid  = threadIdx.x;
    const int wg   = blockIdx.x;
    // XCD-aware remap (XCD = wg&7 assumed): bg's 64 WGs sit on XCDs {2bg,2bg+1}
    const int bg   = (wg & 7) >> 1;             // batch group 0..3
    const int j    = ((wg >> 3) << 1) | (wg & 1); // row group 0..63
    const int lid  = (bg << 6) | j;             // logical id (flag index)
    const bool leader = (wg < 8);               // one WG per XCD (under the map)
    const int r0   = j * ROWS;
    const int b0   = bg * BATS;
    const int wv   = tid >> 6;      // wave 0..3
    const int lane = tid & 63;
    const int lm   = lane & 15;     // A: m index / B: n index / C: col index
    const int quad = lane >> 4;     // 0..3

    // ---- one-time init: stage W_res slice (fp32 -> fp16) into LDS ----
    for (int idx = tid; idx < ROWS * (H_ / 4); idx += 256) {
        int r  = idx >> 9;          // 512 float4 per row
        int c4 = idx & 511;
        const float4 v = ((const float4*)(Wres + (size_t)(r0 + r) * H_))[c4];
        f16* dst = Wr + r * WPAD + c4 * 4;
        dst[0] = (f16)v.x; dst[1] = (f16)v.y; dst[2] = (f16)v.z; dst[3] = (f16)v.w;
    }
    // ---- W_in slice as fp16 hi + lo (precision split) ----
    for (int idx = tid; idx < ROWS * (I_ / 4); idx += 256) {
        int r  = idx >> 5;          // 32 float4 per row
        int c4 = idx & 31;
        const float4 v = ((const float4*)(Win + (size_t)(r0 + r) * I_))[c4];
        float vv[4] = {v.x, v.y, v.z, v.w};
        f16* dh = Whi + r * IPAD + c4 * 4;
        f16* dl = Wlo + r * IPAD + c4 * 4;
        #pragma unroll
        for (int q = 0; q < 4; q++) {
            f16 hi = (f16)vv[q];
            dh[q] = hi;
            dl[q] = (f16)(vv[q] - (float)hi);
        }
    }
    __syncthreads();

    for (int t = 0; t < T_; t++) {
        const u16* hrd = (t & 1) ? ht1 : ht0;   // fresh data carries bit (t>>1)&1
        u16*       hwr = (t & 1) ? ht0 : ht1;   // write h_{t+1}, bit ((t+1)>>1)&1
        const u32  E32 = ((t >> 1) & 1) ? TAG32 : 0u;

        f32x4 acc0 = {0.f, 0.f, 0.f, 0.f};
        f32x4 acc1 = {0.f, 0.f, 0.f, 0.f};

        // ---- x_t @ W_in^T with fp16 hi/lo split (independent work first) ----
        {
            const int kin = wv * 32 + quad * 8;
            const float* xp = x + ((size_t)(b0 + lm) * T_ + t) * I_ + kin;
            float xf[8];
            *(float4*)(xf)     = *(const float4*)(xp);
            *(float4*)(xf + 4) = *(const float4*)(xp + 4);
            f16x8 xhi, xlo;
            #pragma unroll
            for (int qq = 0; qq < 8; qq++) {
                f16 hi = (f16)xf[qq];
                xhi[qq] = hi;
                xlo[qq] = (f16)(xf[qq] - (float)hi);
            }
            f16x8 bh0 = *(const f16x8*)(Whi + lm * IPAD + kin);
            f16x8 bh1 = *(const f16x8*)(Whi + (lm + 16) * IPAD + kin);
            f16x8 bl0 = *(const f16x8*)(Wlo + lm * IPAD + kin);
            f16x8 bl1 = *(const f16x8*)(Wlo + (lm + 16) * IPAD + kin);
            acc0 = __builtin_amdgcn_mfma_f32_16x16x32_f16(xhi, bh0, acc0, 0, 0, 0);
            acc1 = __builtin_amdgcn_mfma_f32_16x16x32_f16(xhi, bh1, acc1, 0, 0, 0);
            acc0 = __builtin_amdgcn_mfma_f32_16x16x32_f16(xlo, bh0, acc0, 0, 0, 0);
            acc1 = __builtin_amdgcn_mfma_f32_16x16x32_f16(xlo, bh1, acc1, 0, 0, 0);
            acc0 = __builtin_amdgcn_mfma_f32_16x16x32_f16(xhi, bl0, acc0, 0, 0, 0);
            acc1 = __builtin_amdgcn_mfma_f32_16x16x32_f16(xhi, bl1, acc1, 0, 0, 0);
        }

        // lane's h base in BYTES: batch row = 4096 B, wave k = 1024 B, quad = 16 B
        const u64 hb = (u64)hrd + ((u64)(b0 + lm) << 12) + (wv << 10) + (quad << 4);
        const f16* w0 = Wr + lm * WPAD + wv * 512 + quad * 8;
        const f16* w1 = Wr + (lm + 16) * WPAD + wv * 512 + quad * 8;
        // lane polls producer (bg, wv*16 + (lane&15)) -> ballot = ready mask
        const int* fp = flags + ((t & 1) * NWG + (bg << 6) + (wv << 4)
                                 + (lane & 15)) * FSTRIDE;

        // ---- streaming consume: poll -> load ready subset -> validate -> MFMA ----
        u32x4 v[16];
        u32 pend = 0xFFFFu;
        int spins = 0;
        while (pend) {
            // leader refreshes this XCD's L2 view so follower loads see fresh h
            if (leader) __builtin_amdgcn_fence(__ATOMIC_ACQUIRE, "agent");
            int f = __hip_atomic_load(fp, __ATOMIC_RELAXED,
                                      __HIP_MEMORY_SCOPE_AGENT);
            u32 ready = (u32)__ballot(f >= t) & 0xFFFFu;
            u32 go = ready & pend;
            if (++spins > 4096) go = pend;      // bailout: flags are hints only
            if (!go) { __builtin_amdgcn_s_sleep(1); continue; }

            // issue L2-cached loads for the newly-ready fragments
            #pragma unroll
            for (int ks = 0; ks < 16; ks++)
                if (go & (1u << ks))
                    asm volatile("global_load_dwordx4 %0, %1, off sc0"
                                 : "=&v"(v[ks]) : "v"(hb + (u64)(ks * 64)));
            asm volatile("s_waitcnt vmcnt(0)" ::: "memory");

            // validate + consume each selected fragment
            #pragma unroll
            for (int ks = 0; ks < 16; ks++) {
                if (!(go & (1u << ks))) continue;
                int rounds = 0;
                for (;;) {
                    u32 bad = ((v[ks][0] & TAG32) ^ E32) | ((v[ks][1] & TAG32) ^ E32)
                            | ((v[ks][2] & TAG32) ^ E32) | ((v[ks][3] & TAG32) ^ E32);
                    if (__all(bad == 0)) break;
                    __builtin_amdgcn_s_sleep(1);
                    if (++rounds < 4) {          // retry via L2
                        asm volatile("global_load_dwordx4 %0, %1, off sc0"
                                     : "=&v"(v[ks]) : "v"(hb + (u64)(ks * 64)));
                    } else {                     // safety valve: coherence point
                        asm volatile("global_load_dwordx4 %0, %1, off sc0 sc1"
                                     : "=&v"(v[ks]) : "v"(hb + (u64)(ks * 64)));
                    }
                    asm volatile("s_waitcnt vmcnt(0)" ::: "memory");
                }
                f16x8 af;
                #pragma unroll
                for (int e = 0; e < 4; e++)
                    ((u32*)&af)[e] = v[ks][e] & ~TAG32;   // clear tag (<=1 ulp)
                f16x8 bf0 = *(const f16x8*)(w0 + ks * 32);   // LDS ds_read_b128
                f16x8 bf1 = *(const f16x8*)(w1 + ks * 32);
                acc0 = __builtin_amdgcn_mfma_f32_16x16x32_f16(af, bf0, acc0, 0, 0, 0);
                acc1 = __builtin_amdgcn_mfma_f32_16x16x32_f16(af, bf1, acc1, 0, 0, 0);
            }
            pend &= ~go;
        }

        // ---- per-wave partials to LDS (C/D layout: col=lane&15, row=quad*4+reg) ----
        {
            float* pw = part + wv * (BATS * PPAD);
            #pragma unroll
            for (int r = 0; r < 4; r++) {
                int m = quad * 4 + r;
                pw[m * PPAD + lm]      = acc0[r];
                pw[m * PPAD + 16 + lm] = acc1[r];
            }
        }
        __syncthreads();

        // ---- reduce 4 waves + tanh + store ----
        if (t == T_ - 1) {
            // final step: fp32 to out, 2 per thread (m = tid>>4, n = (tid&15)*2)
            const int m = tid >> 4;
            const int n = (tid & 15) * 2;
            const int o = m * PPAD + n;
            float s0 = part[o]     + part[BATS * PPAD + o]     + part[2 * BATS * PPAD + o]
                     + part[3 * BATS * PPAD + o];
            float s1 = part[o + 1] + part[BATS * PPAD + o + 1] + part[2 * BATS * PPAD + o + 1]
                     + part[3 * BATS * PPAD + o + 1];
            float* op = out + (size_t)(b0 + m) * H_ + r0 + n;
            op[0] = tanhf(s0);
            op[1] = tanhf(s1);
        } else if (tid < 128) {
            // h store: one u64 = 4 tagged halves per thread (m = tid>>3, n0 = (tid&7)*4)
            const int m  = tid >> 3;
            const int n0 = (tid & 7) * 4;
            const u16 bit = (u16)(((t + 1) >> 1) & 1);
            union { u16 h[4]; u64 u; } pk;
            #pragma unroll
            for (int e = 0; e < 4; e++) {
                const int o = m * PPAD + n0 + e;
                float s = part[o] + part[BATS * PPAD + o] + part[2 * BATS * PPAD + o]
                        + part[3 * BATS * PPAD + o];
                union { f16 f; u16 u; } cv;
                cv.f = (f16)tanhf(s);
                pk.h[e] = (u16)((cv.u & 0xFFFEu) | bit);   // mantissa LSB = tag
            }
            // fire-and-forget write-through to L3; validity is in-band
            __hip_atomic_store((u64*)(hwr + (size_t)(b0 + m) * H_ + r0 + n0),
                               pk.u, __ATOMIC_RELAXED, __HIP_MEMORY_SCOPE_AGENT);
        }

        // protect LDS partials from next step's writes; all h stores ISSUED
        __syncthreads();

        // ---- flag hint publish (after barrier => after all store issues) ----
        if (t < T_ - 1 && tid == 0) {
            __hip_atomic_store(flags + (((t + 1) & 1) * NWG + lid) * FSTRIDE,
                               t + 1, __ATOMIC_RELAXED, __HIP_MEMORY_SCOPE_AGENT);
        }
    }
}

extern "C" void kernel_launch(void* const* d_in, const int* in_sizes, int n_in,
                              void* d_out, int out_size, void* d_ws, size_t ws_size,
                              hipStream_t stream)
{
    (void)in_sizes; (void)n_in; (void)out_size; (void)ws_size;
    const float* x    = (const float*)d_in[0];
    const float* Win  = (const float*)d_in[1];
    const float* Wres = (const float*)d_in[2];
    float* out = (float*)d_out;

    u16* ht0 = (u16*)d_ws;                        // [64][2048] fp16, LSB = tag
    u16* ht1 = ht0 + (size_t)B_ * H_;
    int* flags = (int*)((char*)d_ws + (size_t)2 * B_ * H_ * sizeof(u16));

    // buffer0: 0x00 -> h_0 = 0, tag 0 fresh for t=0; buffer1: 0x01 -> stale
    // until real h_1; flags: 0 (step-0 poll passes: 0 >= 0).
    hipMemsetAsync(d_ws, 0x00, (size_t)B_ * H_ * sizeof(u16), stream);
    hipMemsetAsync((char*)d_ws + (size_t)B_ * H_ * sizeof(u16), 0x01,
                   (size_t)B_ * H_ * sizeof(u16), stream);
    hipMemsetAsync(flags, 0, (size_t)2 * NWG * FSTRIDE * sizeof(int), stream);

    hipFuncSetAttribute((const void*)esn_kernel,
                        hipFuncAttributeMaxDynamicSharedMemorySize, LDS_TOTAL);

    void* args[] = {(void*)&x, (void*)&Win, (void*)&Wres, (void*)&out,
                    (void*)&ht0, (void*)&ht1, (void*)&flags};
    hipLaunchCooperativeKernel((const void*)esn_kernel, dim3(NWG), dim3(256),
                               args, LDS_TOTAL, stream);
}